// Round 1
// 325.149 us; speedup vs baseline: 1.0439x; 1.0439x over previous
//
#include <hip/hip_runtime.h>
#include <cstdint>
#include <cstddef>

// Problem: B=32, C=768, H=W=32 (HW=1024).
// out[b,c,hw] = (0.5 + 0.5 * cos_gate(b,c)) * X[b,c,hw]
// cos_gate = dot(K_c,V_c)/((||K_c||+1e-12)(||V_c||+1e-12)),
// K = Wk @ Xn, V = Wv @ Xn, Xn = X * rsqrt(mean_c X^2 + 1e-6).
//
// This round: single interleaved-A 256x256 8-phase GEMM (T3+T4 counted vmcnt,
// T5 setprio). Wst[2c]=Wk_c, Wst[2c+1]=Wv_c so K/V pair sits in one acc quad.

#define B_   32
#define C_   768
#define HW_  1024
#define CHW_ (C_ * HW_)          // 786432
#define EPS_NORM 1e-6f
#define EPS_COS  1e-12f

using f32x4  = __attribute__((ext_vector_type(4))) float;
using bf16x8 = __attribute__((ext_vector_type(8))) short;   // 8 bf16 = 4 VGPRs

__device__ inline unsigned short f2bf(float f) {
    union { float f; unsigned u; } v; v.f = f;
    unsigned u = v.u;
    u += 0x7fffu + ((u >> 16) & 1u);        // round-to-nearest-even
    return (unsigned short)(u >> 16);
}

// async global->LDS, 16 B per lane. LDS dst is wave-uniform base + lane*16.
__device__ __forceinline__ void load16_lds(const unsigned short* g, short* l) {
    __builtin_amdgcn_global_load_lds(
        (const __attribute__((address_space(1))) unsigned int*)g,
        (__attribute__((address_space(3))) unsigned int*)l,
        16, 0, 0);
}

// Stage one half-tile (128 rows x 64 k, bf16) = 2 x global_load_lds per thread.
// toff = r0*768 + swizzled-chunk byte offset (thread-invariant), rs = global row
// stride between the two calls (A: 128, B: 64). LDS rows land linearly; the
// global source is pre-swizzled chunk^(row&7) to match the read-side XOR.
__device__ __forceinline__ void stage_half(const unsigned short* g, short* l,
                                           size_t toff, int ldsoff, int rs) {
    load16_lds(g + toff,                     l + ldsoff);
    load16_lds(g + toff + (size_t)rs * 768,  l + ldsoff + 4096);
}

// ---------------------------------------------------------------------------
// K1: cast + row-interleave first 1536 rows of W_in (fp32) -> bf16.
// Wst[2c+s] = W[s*768 + c]. grid 1536 blocks x 192 threads (1 float4/thread).
// ---------------------------------------------------------------------------
__global__ void wconv_kernel(const float* __restrict__ W, unsigned short* __restrict__ Wst) {
    const int orow = blockIdx.x;               // 0..1535
    const int c4   = threadIdx.x;              // 0..191
    const int irow = (orow & 1) * 768 + (orow >> 1);
    const float4 v = reinterpret_cast<const float4*>(W + (size_t)irow * 768)[c4];
    ushort4 o;
    o.x = f2bf(v.x); o.y = f2bf(v.y); o.z = f2bf(v.z); o.w = f2bf(v.w);
    reinterpret_cast<ushort4*>(Wst + (size_t)orow * 768)[c4] = o;
}

// ---------------------------------------------------------------------------
// K2: channel sum-of-squares, float4 loads. (unchanged)
// ---------------------------------------------------------------------------
__global__ void sumsq_kernel(const float* __restrict__ X, float* __restrict__ ssum) {
    const int b  = blockIdx.y;
    const int c0 = blockIdx.x * 32;
    const int t  = threadIdx.x;                       // hw quad 0..255
    const float4* xp = reinterpret_cast<const float4*>(X + (size_t)b * CHW_ + (size_t)c0 * HW_) + t;
    float4 s = {0.f, 0.f, 0.f, 0.f};
    #pragma unroll 8
    for (int c = 0; c < 32; ++c) {
        float4 v = xp[c * 256];
        s.x += v.x * v.x; s.y += v.y * v.y; s.z += v.z * v.z; s.w += v.w * v.w;
    }
    float* dst = ssum + b * HW_ + t * 4;
    atomicAdd(dst + 0, s.x);
    atomicAdd(dst + 1, s.y);
    atomicAdd(dst + 2, s.z);
    atomicAdd(dst + 3, s.w);
}

// ---------------------------------------------------------------------------
// K3: Xn_t[b][hw][c] = bf16( X[b][c][hw] * rsqrt(ssum/768 + eps) )  (unchanged)
// ---------------------------------------------------------------------------
__global__ __launch_bounds__(256) void xnt_kernel(const float* __restrict__ X,
                                                  const float* __restrict__ ssum,
                                                  unsigned short* __restrict__ Xnt) {
    const int b   = blockIdx.z;
    const int c0  = blockIdx.y * 64;
    const int hw0 = blockIdx.x * 64;
    const int tid = threadIdx.x;
    __shared__ short T[64][78];

    #pragma unroll
    for (int it = 0; it < 4; ++it) {
        int q  = it * 256 + tid;        // 0..1023
        int r  = q >> 4;                // c row in tile
        int c4 = (q & 15) * 4;          // hw col in tile
        const float4 x = *reinterpret_cast<const float4*>(
            X + (size_t)b * CHW_ + (size_t)(c0 + r) * HW_ + hw0 + c4);
        const float4 s = *reinterpret_cast<const float4*>(ssum + b * HW_ + hw0 + c4);
        ushort4 o;
        o.x = f2bf(x.x * rsqrtf(s.x * (1.f / 768.f) + EPS_NORM));
        o.y = f2bf(x.y * rsqrtf(s.y * (1.f / 768.f) + EPS_NORM));
        o.z = f2bf(x.z * rsqrtf(s.z * (1.f / 768.f) + EPS_NORM));
        o.w = f2bf(x.w * rsqrtf(s.w * (1.f / 768.f) + EPS_NORM));
        *reinterpret_cast<ushort4*>(&T[r][c4]) = o;
    }
    __syncthreads();
    #pragma unroll
    for (int it = 0; it < 2; ++it) {
        int q  = it * 256 + tid;        // 0..511
        int rp = q >> 3;                // hw row
        int cc = (q & 7) * 8;           // c chunk
        __align__(16) unsigned short tmp[8];
        #pragma unroll
        for (int j = 0; j < 8; ++j) tmp[j] = (unsigned short)T[cc + j][rp];
        *reinterpret_cast<uint4*>(
            Xnt + (size_t)b * CHW_ + (size_t)(hw0 + rp) * C_ + c0 + cc) =
            *reinterpret_cast<const uint4*>(tmp);
    }
}

// ---------------------------------------------------------------------------
// K4: 256x256 (BK=64) 8-phase GEMM + fused row reductions.
// 512 threads = 8 waves (2M x 4N), 128x64 output per wave.
// LDS 128 KiB: sA/sB[2 buf][2 half][128][64]. Swizzle: chunk ^= (row&7).
// A half h covers block rows {64h+[0,64)} U {64h+128+[0,64)} (phase-major),
// so each region frees exactly one phase before it is restaged.
// Stage schedule (tiles T0=2it buf0, T1 buf1; prefetch T2,T3):
//   ph1:A(T1)h1  ph2:B(T2)h0  ph3:B(T2)h1  ph4:A(T2)h0+vmcnt(6)
//   ph5:A(T2)h1  ph6:B(T3)h0  ph7:B(T3)h1  ph8:A(T3)h0+vmcnt(6)
// Every consumed half is >=4 stages old at its guarding vmcnt (verified).
// ---------------------------------------------------------------------------
template<int P, bool VM>
__device__ __forceinline__ void phase(const short* Ar, const short* Br,
        const unsigned short* gs, short* ls, size_t toff, int ldsoff, int rs,
        int l15, int wgm64, int wnl64, int slot0, int slot1,
        bf16x8 (&bA)[2][2], bf16x8 (&bB)[4][2], f32x4 (&acc)[8][4]) {
    if constexpr (P == 0) {            // B-frags loaded once per K-tile
        #pragma unroll
        for (int ni = 0; ni < 4; ++ni) {
            const int rB = wnl64 + (ni << 4) + l15;
            bB[ni][0] = *reinterpret_cast<const bf16x8*>(Br + (rB << 6) + slot0);
            bB[ni][1] = *reinterpret_cast<const bf16x8*>(Br + (rB << 6) + slot1);
        }
    }
    #pragma unroll
    for (int s = 0; s < 2; ++s) {      // A-frags mi = 2P, 2P+1
        const int rA = ((((P & 1) << 1) | s) << 4) + l15 + wgm64;
        bA[s][0] = *reinterpret_cast<const bf16x8*>(Ar + (rA << 6) + slot0);
        bA[s][1] = *reinterpret_cast<const bf16x8*>(Ar + (rA << 6) + slot1);
    }
    stage_half(gs, ls, toff, ldsoff, rs);
    if (VM) asm volatile("s_waitcnt vmcnt(6)" ::: "memory");
    __builtin_amdgcn_sched_barrier(0);
    __builtin_amdgcn_s_barrier();
    asm volatile("s_waitcnt lgkmcnt(0)" ::: "memory");
    __builtin_amdgcn_sched_barrier(0);
    __builtin_amdgcn_s_setprio(1);
    #pragma unroll
    for (int s = 0; s < 2; ++s)
        #pragma unroll
        for (int ni = 0; ni < 4; ++ni) {
            acc[(P << 1) | s][ni] = __builtin_amdgcn_mfma_f32_16x16x32_bf16(
                bA[s][0], bB[ni][0], acc[(P << 1) | s][ni], 0, 0, 0);
            acc[(P << 1) | s][ni] = __builtin_amdgcn_mfma_f32_16x16x32_bf16(
                bA[s][1], bB[ni][1], acc[(P << 1) | s][ni], 0, 0, 0);
        }
    __builtin_amdgcn_s_setprio(0);
    __builtin_amdgcn_sched_barrier(0);
    __builtin_amdgcn_s_barrier();
    __builtin_amdgcn_sched_barrier(0);
}

__global__ __launch_bounds__(512, 2) void gemm_kernel(
        const unsigned short* __restrict__ Wst,   // [1536][768] bf16, interleaved K/V
        const unsigned short* __restrict__ Xnt,   // [B][HW][C] bf16
        float* __restrict__ wsA) {
    const int n0   = blockIdx.x * 256;
    const int c0   = blockIdx.y * 256;            // interleaved row base
    const int b    = blockIdx.z;
    const int tid  = threadIdx.x;
    const int lane = tid & 63;
    const int wave = tid >> 6;
    const int l15  = lane & 15;
    const int quad = lane >> 4;
    const int wgm64 = (wave >> 2) << 6;           // A lr offset: 0 / 64
    const int wq    = wave & 3;
    const int wnl64 = (wq & 1) << 6;              // B lr offset within half
    const int hB    = wq >> 1;                    // wave's fixed B half

    const int lb7   = l15 & 7;
    const int slot0 = (quad ^ lb7) << 3;          // k-step 0 swizzled slot (shorts)
    const int slot1 = ((quad + 4) ^ lb7) << 3;    // k-step 1

    __shared__ __align__(16) short sA[2][2][128][64];
    __shared__ __align__(16) short sB[2][2][128][64];

    // staging map: r0 = local row 0..63 per call, chunk pre-swizzled by (r0&7)
    const int r0      = tid >> 3;
    const size_t toff = (size_t)r0 * 768 + (((tid & 7) ^ (r0 & 7)) << 3);
    const int ldsoff  = (r0 & ~7) << 6;           // wave-uniform per 8-lane row group

    const unsigned short* Ab = Wst + (size_t)c0 * 768;
    const unsigned short* Bb = Xnt + (size_t)b * CHW_ + (size_t)n0 * 768;

    f32x4 acc[8][4];
    const f32x4 zero = {0.f, 0.f, 0.f, 0.f};
    #pragma unroll
    for (int i = 0; i < 8; ++i)
        #pragma unroll
        for (int j = 0; j < 4; ++j) acc[i][j] = zero;

    bf16x8 bA[2][2], bB[4][2];

    // prologue: tile0 fully + B(T1)h0/h1 + A(T1)h0  (A(T1)h1 comes in ph1)
    stage_half(Ab,                &sA[0][0][0][0], toff, ldsoff, 128);
    stage_half(Ab + 64 * 768,     &sA[0][1][0][0], toff, ldsoff, 128);
    stage_half(Bb,                &sB[0][0][0][0], toff, ldsoff, 64);
    stage_half(Bb + 128 * 768,    &sB[0][1][0][0], toff, ldsoff, 64);
    stage_half(Bb + 64,           &sB[1][0][0][0], toff, ldsoff, 64);
    stage_half(Bb + 128 * 768 + 64, &sB[1][1][0][0], toff, ldsoff, 64);
    stage_half(Ab + 64,           &sA[1][0][0][0], toff, ldsoff, 128);
    asm volatile("s_waitcnt vmcnt(6)" ::: "memory");   // tile0's 8 loads done
    __builtin_amdgcn_s_barrier();
    __builtin_amdgcn_sched_barrier(0);

    for (int it = 0; it < 6; ++it) {
        const int kT1 = it * 128 + 64;
        int kT2 = it * 128 + 128; if (kT2 >= 768) kT2 -= 768;   // wrap: dead stages
        int kT3 = it * 128 + 192; if (kT3 >= 768) kT3 -= 768;

        // tile T0 (buf0), phases 1-4
        phase<0, false>(&sA[0][0][0][0], &sB[0][hB][0][0],
                        Ab + 64 * 768 + kT1, &sA[1][1][0][0], toff, ldsoff, 128,
                        l15, wgm64, wnl64, slot0, slot1, bA, bB, acc);
        phase<1, false>(&sA[0][0][0][0], nullptr,
                        Bb + kT2,            &sB[0][0][0][0], toff, ldsoff, 64,
                        l15, wgm64, wnl64, slot0, slot1, bA, bB, acc);
        phase<2, false>(&sA[0][1][0][0], nullptr,
                        Bb + 128 * 768 + kT2, &sB[0][1][0][0], toff, ldsoff, 64,
                        l15, wgm64, wnl64, slot0, slot1, bA, bB, acc);
        phase<3, true >(&sA[0][1][0][0], nullptr,
                        Ab + kT2,            &sA[0][0][0][0], toff, ldsoff, 128,
                        l15, wgm64, wnl64, slot0, slot1, bA, bB, acc);
        // tile T1 (buf1), phases 5-8
        phase<0, false>(&sA[1][0][0][0], &sB[1][hB][0][0],
                        Ab + 64 * 768 + kT2, &sA[0][1][0][0], toff, ldsoff, 128,
                        l15, wgm64, wnl64, slot0, slot1, bA, bB, acc);
        phase<1, false>(&sA[1][0][0][0], nullptr,
                        Bb + kT3,            &sB[1][0][0][0], toff, ldsoff, 64,
                        l15, wgm64, wnl64, slot0, slot1, bA, bB, acc);
        phase<2, false>(&sA[1][1][0][0], nullptr,
                        Bb + 128 * 768 + kT3, &sB[1][1][0][0], toff, ldsoff, 64,
                        l15, wgm64, wnl64, slot0, slot1, bA, bB, acc);
        phase<3, true >(&sA[1][1][0][0], nullptr,
                        Ab + kT3,            &sA[1][0][0][0], toff, ldsoff, 128,
                        l15, wgm64, wnl64, slot0, slot1, bA, bB, acc);
    }
    asm volatile("s_waitcnt vmcnt(0)" ::: "memory");   // drain dead prefetches

    // epilogue: rows (4q..4q+3) of each acc quad are (K,V,K,V) of 2 channels.
    // Reduce over 4 n-frags and 16 col-lanes (hw), atomic into wsA.
    #pragma unroll
    for (int mi = 0; mi < 8; ++mi) {
        float d0 = 0.f, e0 = 0.f, f0 = 0.f, d1 = 0.f, e1 = 0.f, f1 = 0.f;
        #pragma unroll
        for (int ni = 0; ni < 4; ++ni) {
            f32x4 a = acc[mi][ni];
            d0 += a[0] * a[1]; e0 += a[0] * a[0]; f0 += a[1] * a[1];
            d1 += a[2] * a[3]; e1 += a[2] * a[2]; f1 += a[3] * a[3];
        }
        #pragma unroll
        for (int off = 1; off < 16; off <<= 1) {
            d0 += __shfl_xor(d0, off); e0 += __shfl_xor(e0, off); f0 += __shfl_xor(f0, off);
            d1 += __shfl_xor(d1, off); e1 += __shfl_xor(e1, off); f1 += __shfl_xor(f1, off);
        }
        if (l15 == 0) {
            const int ch = (c0 >> 1) + wgm64 + (mi << 3) + (quad << 1);
            float* dst = wsA + ((size_t)b * C_ + ch) * 3;
            atomicAdd(dst + 0, d0); atomicAdd(dst + 1, e0); atomicAdd(dst + 2, f0);
            atomicAdd(dst + 3, d1); atomicAdd(dst + 4, e1); atomicAdd(dst + 5, f1);
        }
    }
}

// ---------------------------------------------------------------------------
// K5: out = X * gate. (unchanged)
// ---------------------------------------------------------------------------
__global__ void final_kernel(const float* __restrict__ X, const float* __restrict__ wsA,
                             float* __restrict__ out) {
    const int bc = blockIdx.x;                 // b*768 + c
    const float* a = wsA + (size_t)bc * 3;
    const float pd = a[0], pk = a[1], pv = a[2];
    const float A = pd / ((sqrtf(pk) + EPS_COS) * (sqrtf(pv) + EPS_COS));
    const float g = 0.5f * A + 0.5f;
    const size_t i4 = (size_t)bc * 256 + threadIdx.x;
    float4 x = reinterpret_cast<const float4*>(X)[i4];
    float4 o;
    o.x = x.x * g; o.y = x.y * g; o.z = x.z * g; o.w = x.w * g;
    reinterpret_cast<float4*>(out)[i4] = o;
}

// ---------------------------------------------------------------------------
extern "C" void kernel_launch(void* const* d_in, const int* in_sizes, int n_in,
                              void* d_out, int out_size, void* d_ws, size_t ws_size,
                              hipStream_t stream) {
    const float* X = (const float*)d_in[0];   // [32,768,32,32]
    const float* W = (const float*)d_in[1];   // [2304,768]
    float* out = (float*)d_out;

    // workspace layout (bytes):
    //   [0,       294912)   wsA   float[32*768*3]  (dot, nk2, nv2)
    //   [294912,  425984)   ssum  float[32*1024]
    //   [425984,  2785280)  Wst   bf16[1536*768]   (interleaved K/V rows)
    //   [2785280, 53116928) Xnt   bf16[32][1024][768]
    char* ws = (char*)d_ws;
    float* wsA           = (float*)ws;
    float* ssum          = (float*)(ws + 294912);
    unsigned short* Wst  = (unsigned short*)(ws + 425984);
    unsigned short* Xnt  = (unsigned short*)(ws + 2785280);

    hipMemsetAsync(ws, 0, 425984, stream);    // zero wsA + ssum

    wconv_kernel<<<dim3(1536),       192, 0, stream>>>(W, Wst);
    sumsq_kernel<<<dim3(24, 32),     256, 0, stream>>>(X, ssum);
    xnt_kernel  <<<dim3(16, 12, 32), 256, 0, stream>>>(X, ssum, Xnt);
    gemm_kernel <<<dim3(4, 6, 32),   512, 0, stream>>>(Wst, Xnt, wsA);
    final_kernel<<<dim3(24576),      256, 0, stream>>>(X, wsA, out);
}